// Round 3
// baseline (95.108 us; speedup 1.0000x reference)
//
#include <hip/hip_runtime.h>
#include <hip/hip_bf16.h>

// Problem constants: B=128, C=21, L=2048, W=32, S=8, O=16, NW=252, NK=4032, K=672
#define Bb   128
#define Cc   21
#define Ll   2048
#define Ss   8
#define Oo   16
#define NWw  252
#define NKk  4032
#define Kk   672
#define KP   680   // LDS pitch (bf16): 85 x 16B granules, odd -> conflict-light b128

typedef __attribute__((ext_vector_type(8))) short  short8;  // 8 bf16 = 4 VGPRs
typedef __attribute__((ext_vector_type(4))) float  f32x4;

static __device__ __forceinline__ unsigned short f2bf(float f) {
    union { __hip_bfloat16 h; unsigned short u; } cv;
    cv.h = __float2bfloat16(f);
    return cv.u;
}

// Grid: (252 windows, 2 batch-halves). Block: 512 threads = 8 waves =
// 4 m-tiles (16 batch rows each) x 2 k-halves (c-steps 0-10 / 11-20).
// k-split doubles resident waves' memory-level parallelism; partials are
// combined via a 4 KB LDS buffer. __launch_bounds__(512,4) caps VGPR at 128
// so 2 blocks/CU co-reside -> 16 waves/CU.
__global__ __launch_bounds__(512, 4)
void fb_fwd(const float* __restrict__ x, const float* __restrict__ w,
            float* __restrict__ out) {
    __shared__ unsigned short ws[Oo * KP];   // 21.8 KB bf16 weight tile [o][k]
    __shared__ f32x4 part[4 * 64];           // 4 KB k-half partials

    const int j    = blockIdx.x;
    const int bh   = blockIdx.y;                          // batch half
    const int s    = (j < NWw - 1) ? j * Ss : (Ll - 32);  // STARTS[j], mult of 8
    const int tid  = threadIdx.x;
    const int lane = tid & 63;
    const int wv   = tid >> 6;       // 0..7
    const int mt   = wv & 3;         // m-tile within the 64-row half
    const int kh   = wv >> 2;        // k-half 0/1
    const int col  = lane & 15;      // MFMA m-row (A) / n-col (B)
    const int quad = lane >> 4;      // k-chunk selector

    // ---- stage weight[j]: 16 x 672 fp32 -> bf16 LDS, [o][k] (B^T) ----
    {
        const float4* wj4 = (const float4*)(w + (size_t)j * Oo * Kk);
        for (int t = tid; t < Oo * (Kk / 4); t += 512) {   // 2688 float4
            float4 v = wj4[t];
            int o = t / (Kk / 4);                           // Kk/4 = 168
            int r = t - o * (Kk / 4);
            ushort4 p = make_ushort4(f2bf(v.x), f2bf(v.y), f2bf(v.z), f2bf(v.w));
            *(ushort4*)&ws[o * KP + r * 4] = p;
        }
    }
    __syncthreads();

    const int row = bh * 64 + mt * 16 + col;
    const float* xrow = x + ((size_t)row * Cc) * Ll + s + quad * 8;
    const unsigned short* wrow = &ws[col * KP + quad * 8];

    f32x4 acc = {0.f, 0.f, 0.f, 0.f};

#define KSTEP(c)                                                            \
    {                                                                       \
        const float4 a0 = *(const float4*)(xrow + (size_t)(c) * Ll);        \
        const float4 a1 = *(const float4*)(xrow + (size_t)(c) * Ll + 4);    \
        short8 a;                                                           \
        a[0] = (short)f2bf(a0.x); a[1] = (short)f2bf(a0.y);                 \
        a[2] = (short)f2bf(a0.z); a[3] = (short)f2bf(a0.w);                 \
        a[4] = (short)f2bf(a1.x); a[5] = (short)f2bf(a1.y);                 \
        a[6] = (short)f2bf(a1.z); a[7] = (short)f2bf(a1.w);                 \
        const short8 bfr = *(const short8*)(wrow + (c) * 32);               \
        acc = __builtin_amdgcn_mfma_f32_16x16x32_bf16(a, bfr, acc, 0, 0, 0);\
    }

    if (kh == 0) {
#pragma unroll
        for (int c = 0; c < 11; ++c) KSTEP(c);
    } else {
#pragma unroll
        for (int c = 11; c < 21; ++c) KSTEP(c);
        part[mt * 64 + lane] = acc;
    }
    __syncthreads();

    if (kh == 0) {
        acc += part[mt * 64 + lane];
        // C/D layout: col = lane&15, row = quad*4 + reg
        const int rbase = bh * 64 + mt * 16 + quad * 4;
        float* op = out + (size_t)rbase * NKk + j * 16 + col;
#pragma unroll
        for (int r = 0; r < 4; ++r)
            op[(size_t)r * NKk] = acc[r];
    }
#undef KSTEP
}

extern "C" void kernel_launch(void* const* d_in, const int* in_sizes, int n_in,
                              void* d_out, int out_size, void* d_ws, size_t ws_size,
                              hipStream_t stream) {
    const float* x = (const float*)d_in[0];   // (128, 21, 2048) fp32
    const float* w = (const float*)d_in[1];   // (4032, 672) fp32
    float* out = (float*)d_out;               // (128, 4032) fp32
    fb_fwd<<<dim3(NWw, 2), dim3(512), 0, stream>>>(x, w, out);
}

// Round 4
// 85.811 us; speedup vs baseline: 1.1083x; 1.1083x over previous
//
#include <hip/hip_runtime.h>
#include <hip/hip_bf16.h>

// Problem constants: B=128, C=21, L=2048, W=32, S=8, O=16, NW=252, NK=4032, K=672
#define Bb   128
#define Cc   21
#define Ll   2048
#define Ss   8
#define Oo   16
#define NWw  252
#define NKk  4032
#define Kk   672
#define KP   680   // LDS pitch (bf16): 85 x 16B granules, odd -> conflict-light b128

typedef __attribute__((ext_vector_type(8))) short  short8;  // 8 bf16 = 4 VGPRs
typedef __attribute__((ext_vector_type(4))) float  f32x4;

static __device__ __forceinline__ unsigned short f2bf(float f) {
    union { __hip_bfloat16 h; unsigned short u; } cv;
    cv.h = __float2bfloat16(f);
    return cv.u;
}

// Grid: 512 blocks of 256 threads (8 tail blocks idle). XCD-aware mapping:
// assuming round-robin dispatch, XCD r = bid%8 owns windows [r*32, r*32+32),
// two batch-half blocks per window. Its x working set (columns [r*256,
// r*256+288), 3.1 MB) fits the 4 MB per-XCD L2, so the 4x window-overlap
// re-read of x is served from L2 instead of refetched -> FETCH_SIZE ~halves.
// Block: 4 waves, each one 16-batch m-tile, full K=672 (21 MFMA), A-fragments
// loaded straight from global (fp32->bf16 in-register); only the 21.8 KB bf16
// weight tile lives in LDS. (256,3): VGPR cap 170, 3 blocks/CU co-resident.
__global__ __launch_bounds__(256, 3)
void fb_fwd(const float* __restrict__ x, const float* __restrict__ w,
            float* __restrict__ out) {
    __shared__ unsigned short ws[Oo * KP];

    const int bid = blockIdx.x;
    const int r   = bid & 7;          // XCD id (dispatch heuristic)
    const int t   = bid >> 3;         // 0..63 within XCD
    const int j   = r * 32 + (t >> 1);
    const int bh  = t & 1;            // batch half
    if (j >= NWw) return;             // uniform per block

    const int s    = (j < NWw - 1) ? j * Ss : (Ll - 32);  // STARTS[j]
    const int tid  = threadIdx.x;
    const int lane = tid & 63;
    const int wv   = tid >> 6;       // 0..3: m-tile id
    const int col  = lane & 15;      // MFMA m-row (A) / n-col (B)
    const int quad = lane >> 4;      // k-chunk selector

    // ---- stage weight[j]: 16 x 672 fp32 -> bf16 LDS, [o][k] (B^T) ----
    {
        const float4* wj4 = (const float4*)(w + (size_t)j * Oo * Kk);
        for (int ti = tid; ti < Oo * (Kk / 4); ti += 256) {   // 2688 float4
            float4 v = wj4[ti];
            int o  = ti / (Kk / 4);                            // Kk/4 = 168
            int rr = ti - o * (Kk / 4);
            ushort4 p = make_ushort4(f2bf(v.x), f2bf(v.y), f2bf(v.z), f2bf(v.w));
            *(ushort4*)&ws[o * KP + rr * 4] = p;
        }
    }
    __syncthreads();

    const int row = bh * 64 + wv * 16 + col;
    const float* xrow = x + ((size_t)row * Cc) * Ll + s + quad * 8;
    const unsigned short* wrow = &ws[col * KP + quad * 8];

    f32x4 acc = {0.f, 0.f, 0.f, 0.f};
#pragma unroll
    for (int c = 0; c < Cc; ++c) {                 // 21 k-steps of 32
        const float4 a0 = *(const float4*)(xrow + (size_t)c * Ll);
        const float4 a1 = *(const float4*)(xrow + (size_t)c * Ll + 4);
        short8 a;
        a[0] = (short)f2bf(a0.x); a[1] = (short)f2bf(a0.y);
        a[2] = (short)f2bf(a0.z); a[3] = (short)f2bf(a0.w);
        a[4] = (short)f2bf(a1.x); a[5] = (short)f2bf(a1.y);
        a[6] = (short)f2bf(a1.z); a[7] = (short)f2bf(a1.w);
        const short8 bfr = *(const short8*)(wrow + c * 32);
        acc = __builtin_amdgcn_mfma_f32_16x16x32_bf16(a, bfr, acc, 0, 0, 0);
    }

    // ---- C/D layout: col = lane&15, row = quad*4 + reg ----
    const int rbase = bh * 64 + wv * 16 + quad * 4;
    float* op = out + (size_t)rbase * NKk + j * 16 + col;
#pragma unroll
    for (int rr = 0; rr < 4; ++rr)
        op[(size_t)rr * NKk] = acc[rr];
}

extern "C" void kernel_launch(void* const* d_in, const int* in_sizes, int n_in,
                              void* d_out, int out_size, void* d_ws, size_t ws_size,
                              hipStream_t stream) {
    const float* x = (const float*)d_in[0];   // (128, 21, 2048) fp32
    const float* w = (const float*)d_in[1];   // (4032, 672) fp32
    float* out = (float*)d_out;               // (128, 4032) fp32
    fb_fwd<<<dim3(512), dim3(256), 0, stream>>>(x, w, out);
}

// Round 5
// 84.441 us; speedup vs baseline: 1.1263x; 1.0162x over previous
//
#include <hip/hip_runtime.h>
#include <hip/hip_bf16.h>

// Problem constants: B=128, C=21, L=2048, W=32, S=8, O=16, NW=252, NK=4032, K=672
#define Bb   128
#define Cc   21
#define Ll   2048
#define Ss   8
#define Oo   16
#define NWw  252
#define NKk  4032
#define Kk   672
#define KP   680   // LDS pitch (bf16): 85 x 16B granules, odd -> conflict-light b128

typedef __attribute__((ext_vector_type(8))) short  short8;  // 8 bf16 = 4 VGPRs
typedef __attribute__((ext_vector_type(4))) float  f32x4;

static __device__ __forceinline__ unsigned short f2bf(float f) {
    union { __hip_bfloat16 h; unsigned short u; } cv;
    cv.h = __float2bfloat16(f);
    return cv.u;
}

// ---- Pass 1: stream-convert x (22 MB fp32) -> bf16 (11 MB) in d_ws. ----
// Pure BW-bound: 33 MB traffic ~6 us. Halves pass-2 bytes/element so the
// same VGPR budget holds 2x the elements in flight, and removes the
// load->cvt chain from the MFMA hot loop.
__global__ __launch_bounds__(256)
void cvt_x(const float* __restrict__ x, unsigned short* __restrict__ xb) {
    const int total4 = Bb * Cc * Ll / 4;            // 1,376,256 float4
    for (int t = blockIdx.x * 256 + threadIdx.x; t < total4;
         t += gridDim.x * 256) {
        float4 v = ((const float4*)x)[t];
        ushort4 p = make_ushort4(f2bf(v.x), f2bf(v.y), f2bf(v.z), f2bf(v.w));
        ((ushort4*)xb)[t] = p;
    }
}

// ---- Pass 2: one 512-thr block per window; 8 waves x 16-row m-tiles = all
// 128 batches. XCD swizzle (R4, validated): XCD r=bid%8 owns windows
// [32r,32r+32) -> 1.5 MB bf16 x-slab fits 4 MB per-XCD L2, so the 4x
// window-overlap re-read is L2-served. Each wave BATCH-ISSUES its entire
// K=672 A-slice: 21 x 16B global loads into a register array (84 VGPR, all
// in flight at once) -> ~2.7 KB/CU outstanding vs ~2 KB before at half the
// delivered elements. MFMA sweep then runs from registers + LDS B-frags.
__global__ __launch_bounds__(512)
void fb_mm(const unsigned short* __restrict__ xb, const float* __restrict__ w,
           float* __restrict__ out) {
    __shared__ unsigned short ws[Oo * KP];

    const int bid = blockIdx.x;
    const int j   = (bid & 7) * 32 + (bid >> 3);          // XCD-grouped window
    if (j >= NWw) return;                                  // 4 tail blocks idle
    const int s    = (j < NWw - 1) ? j * Ss : (Ll - 32);  // STARTS[j], mult of 8
    const int tid  = threadIdx.x;
    const int lane = tid & 63;
    const int wv   = tid >> 6;       // 0..7: m-tile id (16 batch rows each)
    const int col  = lane & 15;      // MFMA m-row (A) / n-col (B)
    const int quad = lane >> 4;      // k-chunk selector

    // stage weight[j]: 16 x 672 fp32 -> bf16 LDS, [o][k] (B^T)
    {
        const float4* wj4 = (const float4*)(w + (size_t)j * Oo * Kk);
        for (int t = tid; t < Oo * (Kk / 4); t += 512) {   // 2688 float4
            float4 v = wj4[t];
            int o = t / (Kk / 4);                           // Kk/4 = 168
            int r = t - o * (Kk / 4);
            ushort4 p = make_ushort4(f2bf(v.x), f2bf(v.y), f2bf(v.z), f2bf(v.w));
            *(ushort4*)&ws[o * KP + r * 4] = p;
        }
    }

    // batch-issue all 21 A-fragments (bf16, 16B/lane, 16B-aligned)
    const unsigned short* xrow =
        xb + ((size_t)(wv * 16 + col) * Cc) * Ll + s + quad * 8;
    short8 afr[Cc];
#pragma unroll
    for (int c = 0; c < Cc; ++c)
        afr[c] = *(const short8*)(xrow + (size_t)c * Ll);

    __syncthreads();

    const unsigned short* wrow = &ws[col * KP + quad * 8];
    f32x4 acc = {0.f, 0.f, 0.f, 0.f};
#pragma unroll
    for (int c = 0; c < Cc; ++c)
        acc = __builtin_amdgcn_mfma_f32_16x16x32_bf16(
            afr[c], *(const short8*)(wrow + c * 32), acc, 0, 0, 0);

    // C/D layout: col = lane&15, row = quad*4 + reg
    const int rbase = wv * 16 + quad * 4;
    float* op = out + (size_t)rbase * NKk + j * 16 + col;
#pragma unroll
    for (int r = 0; r < 4; ++r)
        op[(size_t)r * NKk] = acc[r];
}

extern "C" void kernel_launch(void* const* d_in, const int* in_sizes, int n_in,
                              void* d_out, int out_size, void* d_ws, size_t ws_size,
                              hipStream_t stream) {
    const float* x = (const float*)d_in[0];   // (128, 21, 2048) fp32
    const float* w = (const float*)d_in[1];   // (4032, 672) fp32
    float* out = (float*)d_out;               // (128, 4032) fp32
    unsigned short* xb = (unsigned short*)d_ws;  // 11 MB bf16 x
    cvt_x<<<dim3(1344), dim3(256), 0, stream>>>(x, xb);
    fb_mm<<<dim3(256), dim3(512), 0, stream>>>(xb, w, out);
}